// Round 1
// baseline (669.060 us; speedup 1.0000x reference)
//
#include <hip/hip_runtime.h>
#include <hip/hip_bf16.h>

// Problem sizes (fixed by reference setup_inputs):
//   B=16, N_LOG=512, N_PHYS(Q)=2048, E=2048
#define BATCH 16
#define NLOG 512
#define Q 2048
#define NEDGE 2048
#define M_TOT (BATCH * NLOG)   // 8192 GEMM rows
#define K_TOT Q                // 2048
#define N_TOT Q                // 2048

typedef short short8 __attribute__((ext_vector_type(8)));
typedef float f32x4 __attribute__((ext_vector_type(4)));
typedef unsigned short us8 __attribute__((ext_vector_type(8)));

// ---------------------------------------------------------------------------
// K1: convert P (fp32) -> Pb (bf16). 16.78M elements, 4 per thread.
__global__ __launch_bounds__(256) void cvt_p(const float* __restrict__ P,
                                             __hip_bfloat16* __restrict__ Pb) {
    int i = (blockIdx.x * 256 + threadIdx.x) * 4;
    float4 v = *(const float4*)(P + i);
    Pb[i + 0] = __float2bfloat16(v.x);
    Pb[i + 1] = __float2bfloat16(v.y);
    Pb[i + 2] = __float2bfloat16(v.z);
    Pb[i + 3] = __float2bfloat16(v.w);
}

// ---------------------------------------------------------------------------
// K2: build Abt[q][p] = (d_hw[p][q] == 1) ? 1 : 0 (bf16), via 32x32 LDS
// transpose so both global read and write are coalesced.
__global__ __launch_bounds__(256) void build_abt(const int* __restrict__ d_hw,
                                                 __hip_bfloat16* __restrict__ Abt) {
    __shared__ __hip_bfloat16 tile[32][33];
    int q0 = blockIdx.x * 32;   // source col / dest row block
    int p0 = blockIdx.y * 32;   // source row / dest col block
    int tx = threadIdx.x & 31;
    int ty = threadIdx.x >> 5;  // 0..7
    for (int s = 0; s < 32; s += 8) {
        int p = p0 + ty + s;
        int v = d_hw[(size_t)p * Q + q0 + tx];
        tile[ty + s][tx] = __float2bfloat16(v == 1 ? 1.0f : 0.0f);
    }
    __syncthreads();
    for (int s = 0; s < 32; s += 8) {
        // dest row q = q0 + ty + s, dest col p = p0 + tx
        Abt[(size_t)(q0 + ty + s) * Q + p0 + tx] = tile[tx][ty + s];
    }
}

// ---------------------------------------------------------------------------
// K3: GEMM  C[M,N] = A[M,K] * Bt[N,K]^T   (all bf16, fp32 accumulate,
// bf16 output). 128x128 C-tile per 256-thread block, 4 waves in 2x2 grid,
// each wave 4x4 grid of 16x16x32 MFMAs. global_load_lds width-16 staging.
__global__ __launch_bounds__(256) void gemm_bt(const short* __restrict__ A,
                                               const short* __restrict__ Bt,
                                               __hip_bfloat16* __restrict__ C) {
    __shared__ short lds[8192];          // As: [128][32] then Bs: [128][32]
    short* As = lds;
    short* Bs = lds + 4096;

    const int t = threadIdx.x;
    const int w = t >> 6;                // wave 0..3
    const int l = t & 63;
    const int wr = w >> 1, wc = w & 1;   // 2x2 wave grid
    const int quad = l >> 4;             // 0..3
    const int lane16 = l & 15;

    const int m0 = blockIdx.x * 128;
    const int n0 = blockIdx.y * 128;

    // staging indices: thread t loads 16B = 8 bf16; 256 threads cover
    // 64 rows x 32 k per call; 2 calls per tile.
    const int s_row = t >> 2;            // 0..63
    const int s_col = (t & 3) * 8;       // k element offset

    f32x4 acc[4][4] = {};

    for (int k0 = 0; k0 < K_TOT; k0 += 32) {
        const short* gA0 = A + (size_t)(m0 + s_row) * K_TOT + k0 + s_col;
        const short* gA1 = A + (size_t)(m0 + s_row + 64) * K_TOT + k0 + s_col;
        const short* gB0 = Bt + (size_t)(n0 + s_row) * K_TOT + k0 + s_col;
        const short* gB1 = Bt + (size_t)(n0 + s_row + 64) * K_TOT + k0 + s_col;
        // LDS dest is wave-uniform base + lane*16
        __builtin_amdgcn_global_load_lds(
            (const __attribute__((address_space(1))) void*)gA0,
            (__attribute__((address_space(3))) void*)(As + w * 512), 16, 0, 0);
        __builtin_amdgcn_global_load_lds(
            (const __attribute__((address_space(1))) void*)gA1,
            (__attribute__((address_space(3))) void*)(As + 2048 + w * 512), 16, 0, 0);
        __builtin_amdgcn_global_load_lds(
            (const __attribute__((address_space(1))) void*)gB0,
            (__attribute__((address_space(3))) void*)(Bs + w * 512), 16, 0, 0);
        __builtin_amdgcn_global_load_lds(
            (const __attribute__((address_space(1))) void*)gB1,
            (__attribute__((address_space(3))) void*)(Bs + 2048 + w * 512), 16, 0, 0);
        __syncthreads();

        short8 af[4], bfr[4];
        #pragma unroll
        for (int i = 0; i < 4; i++) {
            af[i]  = *(const short8*)(As + (wr * 64 + i * 16 + lane16) * 32 + quad * 8);
            bfr[i] = *(const short8*)(Bs + (wc * 64 + i * 16 + lane16) * 32 + quad * 8);
        }
        #pragma unroll
        for (int i = 0; i < 4; i++)
            #pragma unroll
            for (int j = 0; j < 4; j++)
                acc[i][j] = __builtin_amdgcn_mfma_f32_16x16x32_bf16(
                    af[i], bfr[j], acc[i][j], 0, 0, 0);
        __syncthreads();
    }

    // epilogue: C/D layout col = lane&15, row = quad*4 + reg
    #pragma unroll
    for (int i = 0; i < 4; i++) {
        #pragma unroll
        for (int j = 0; j < 4; j++) {
            #pragma unroll
            for (int r = 0; r < 4; r++) {
                int row = m0 + wr * 64 + i * 16 + quad * 4 + r;
                int col = n0 + wc * 64 + j * 16 + lane16;
                C[(size_t)row * N_TOT + col] = __float2bfloat16(acc[i][j][r]);
            }
        }
    }
}

// ---------------------------------------------------------------------------
// K4: per-edge dot  score = sum_q PAb[b,src,q] * Pb[b,dst,q], accumulate
// w*score into adj_acc[b]. One block per (b,e); 256 thr x 8 bf16 = 2048 = Q.
__global__ __launch_bounds__(256) void edge_dot(const __hip_bfloat16* __restrict__ PAb,
                                                const __hip_bfloat16* __restrict__ Pb,
                                                const int* __restrict__ esrc,
                                                const int* __restrict__ edst,
                                                const float* __restrict__ ew,
                                                float* __restrict__ adj_acc) {
    int be = blockIdx.x;
    int b = be >> 11;          // /NEDGE
    int e = be & (NEDGE - 1);
    int src = esrc[b * NEDGE + e];
    int dst = edst[b * NEDGE + e];
    const unsigned short* gi = (const unsigned short*)PAb + ((size_t)b * NLOG + src) * Q;
    const unsigned short* gj = (const unsigned short*)Pb + ((size_t)b * NLOG + dst) * Q;
    int t = threadIdx.x;
    us8 a = *(const us8*)(gi + t * 8);
    us8 c = *(const us8*)(gj + t * 8);
    float sum = 0.f;
    #pragma unroll
    for (int k = 0; k < 8; k++) {
        float fa = __uint_as_float((unsigned)a[k] << 16);
        float fc = __uint_as_float((unsigned)c[k] << 16);
        sum += fa * fc;
    }
    #pragma unroll
    for (int off = 32; off > 0; off >>= 1) sum += __shfl_xor(sum, off);
    __shared__ float wred[4];
    if ((t & 63) == 0) wred[t >> 6] = sum;
    __syncthreads();
    if (t == 0) {
        float tot = wred[0] + wred[1] + wred[2] + wred[3];
        atomicAdd(&adj_acc[b], ew[b * NEDGE + e] * tot);
    }
}

// ---------------------------------------------------------------------------
// K5: loss = -mean_b( adj_acc[b] / max(sum_e w, eps) )
__global__ __launch_bounds__(256) void finalize(const float* __restrict__ ew,
                                                const float* __restrict__ adj_acc,
                                                float* __restrict__ out) {
    __shared__ float red[256];
    __shared__ float loss_s;
    int t = threadIdx.x;
    if (t == 0) loss_s = 0.f;
    for (int b = 0; b < BATCH; b++) {
        float s = 0.f;
        for (int e = t; e < NEDGE; e += 256) s += ew[b * NEDGE + e];
        red[t] = s;
        __syncthreads();
        for (int st = 128; st > 0; st >>= 1) {
            if (t < st) red[t] += red[t + st];
            __syncthreads();
        }
        if (t == 0) loss_s += adj_acc[b] / fmaxf(red[0], 1e-8f);
        __syncthreads();
    }
    if (t == 0) out[0] = -loss_s / (float)BATCH;
}

// ---------------------------------------------------------------------------
extern "C" void kernel_launch(void* const* d_in, const int* in_sizes, int n_in,
                              void* d_out, int out_size, void* d_ws, size_t ws_size,
                              hipStream_t stream) {
    const float* P    = (const float*)d_in[0];
    const int* d_hw   = (const int*)d_in[1];
    const int* esrc   = (const int*)d_in[2];
    const int* edst   = (const int*)d_in[3];
    const float* ew   = (const float*)d_in[4];
    float* out        = (float*)d_out;

    char* ws = (char*)d_ws;
    // workspace layout (bytes):
    //   Pb  : bf16 [B*N*Q]      = 33,554,432
    //   Abt : bf16 [Q*Q]        =  8,388,608   (offset 33,554,432)
    //   PAb : bf16 [B*N*Q]      = 33,554,432   (offset 41,943,040)
    //   adj : f32  [16]                          (offset 75,497,472)
    __hip_bfloat16* Pb  = (__hip_bfloat16*)ws;
    __hip_bfloat16* Abt = (__hip_bfloat16*)(ws + 33554432);
    __hip_bfloat16* PAb = (__hip_bfloat16*)(ws + 41943040);
    float* adj          = (float*)(ws + 75497472);

    hipMemsetAsync(adj, 0, BATCH * sizeof(float), stream);

    cvt_p<<<M_TOT * Q / (256 * 4), 256, 0, stream>>>(P, Pb);
    build_abt<<<dim3(Q / 32, Q / 32), 256, 0, stream>>>(d_hw, Abt);
    gemm_bt<<<dim3(M_TOT / 128, N_TOT / 128), 256, 0, stream>>>(
        (const short*)Pb, (const short*)Abt, PAb);
    edge_dot<<<BATCH * NEDGE, 256, 0, stream>>>(PAb, Pb, esrc, edst, ew, adj);
    finalize<<<1, 256, 0, stream>>>(ew, adj, out);
}

// Round 2
// 290.014 us; speedup vs baseline: 2.3070x; 2.3070x over previous
//
#include <hip/hip_runtime.h>
#include <hip/hip_bf16.h>

// Problem sizes (fixed by reference setup_inputs):
//   B=16, N_LOG=512, N_PHYS(Q)=2048, E=2048
#define BATCH 16
#define NLOG 512
#define Q 2048
#define NEDGE 2048
#define M_TOT (BATCH * NLOG)   // 8192 GEMM rows
#define K_TOT Q                // 2048
#define N_TOT Q                // 2048

typedef short short8 __attribute__((ext_vector_type(8)));
typedef float f32x4 __attribute__((ext_vector_type(4)));
typedef unsigned short us8 __attribute__((ext_vector_type(8)));

// ---------------------------------------------------------------------------
// K1: convert P (fp32) -> Pb (bf16). 16.78M elements, 4 per thread.
__global__ __launch_bounds__(256) void cvt_p(const float* __restrict__ P,
                                             __hip_bfloat16* __restrict__ Pb) {
    int i = (blockIdx.x * 256 + threadIdx.x) * 4;
    float4 v = *(const float4*)(P + i);
    Pb[i + 0] = __float2bfloat16(v.x);
    Pb[i + 1] = __float2bfloat16(v.y);
    Pb[i + 2] = __float2bfloat16(v.z);
    Pb[i + 3] = __float2bfloat16(v.w);
}

// ---------------------------------------------------------------------------
// K2: build Abt[q][p] = (d_hw[p][q] == 1) ? 1 : 0 (bf16), via 32x32 LDS
// transpose so both global read and write are coalesced.
__global__ __launch_bounds__(256) void build_abt(const int* __restrict__ d_hw,
                                                 __hip_bfloat16* __restrict__ Abt) {
    __shared__ __hip_bfloat16 tile[32][33];
    int q0 = blockIdx.x * 32;   // source col / dest row block
    int p0 = blockIdx.y * 32;   // source row / dest col block
    int tx = threadIdx.x & 31;
    int ty = threadIdx.x >> 5;  // 0..7
    for (int s = 0; s < 32; s += 8) {
        int p = p0 + ty + s;
        int v = d_hw[(size_t)p * Q + q0 + tx];
        tile[ty + s][tx] = __float2bfloat16(v == 1 ? 1.0f : 0.0f);
    }
    __syncthreads();
    for (int s = 0; s < 32; s += 8) {
        Abt[(size_t)(q0 + ty + s) * Q + p0 + tx] = tile[tx][ty + s];
    }
}

// ---------------------------------------------------------------------------
// K3: GEMM  C[M,N] = A[M,K] * Bt[N,K]^T   (all bf16, fp32 accumulate,
// bf16 output). 128x128 C-tile per 256-thread block, 4 waves in 2x2 grid,
// each wave 4x4 grid of 16x16x32 MFMAs. global_load_lds width-16 staging.
__global__ __launch_bounds__(256) void gemm_bt(const short* __restrict__ A,
                                               const short* __restrict__ Bt,
                                               __hip_bfloat16* __restrict__ C) {
    __shared__ short lds[8192];          // As: [128][32] then Bs: [128][32]
    short* As = lds;
    short* Bs = lds + 4096;

    const int t = threadIdx.x;
    const int w = t >> 6;                // wave 0..3
    const int wr = w >> 1, wc = w & 1;   // 2x2 wave grid
    const int l = t & 63;
    const int quad = l >> 4;             // 0..3
    const int lane16 = l & 15;

    const int m0 = blockIdx.x * 128;
    const int n0 = blockIdx.y * 128;

    const int s_row = t >> 2;            // 0..63
    const int s_col = (t & 3) * 8;       // k element offset

    f32x4 acc[4][4] = {};

    for (int k0 = 0; k0 < K_TOT; k0 += 32) {
        const short* gA0 = A + (size_t)(m0 + s_row) * K_TOT + k0 + s_col;
        const short* gA1 = A + (size_t)(m0 + s_row + 64) * K_TOT + k0 + s_col;
        const short* gB0 = Bt + (size_t)(n0 + s_row) * K_TOT + k0 + s_col;
        const short* gB1 = Bt + (size_t)(n0 + s_row + 64) * K_TOT + k0 + s_col;
        __builtin_amdgcn_global_load_lds(
            (const __attribute__((address_space(1))) void*)gA0,
            (__attribute__((address_space(3))) void*)(As + w * 512), 16, 0, 0);
        __builtin_amdgcn_global_load_lds(
            (const __attribute__((address_space(1))) void*)gA1,
            (__attribute__((address_space(3))) void*)(As + 2048 + w * 512), 16, 0, 0);
        __builtin_amdgcn_global_load_lds(
            (const __attribute__((address_space(1))) void*)gB0,
            (__attribute__((address_space(3))) void*)(Bs + w * 512), 16, 0, 0);
        __builtin_amdgcn_global_load_lds(
            (const __attribute__((address_space(1))) void*)gB1,
            (__attribute__((address_space(3))) void*)(Bs + 2048 + w * 512), 16, 0, 0);
        __syncthreads();

        short8 af[4], bfr[4];
        #pragma unroll
        for (int i = 0; i < 4; i++) {
            af[i]  = *(const short8*)(As + (wr * 64 + i * 16 + lane16) * 32 + quad * 8);
            bfr[i] = *(const short8*)(Bs + (wc * 64 + i * 16 + lane16) * 32 + quad * 8);
        }
        #pragma unroll
        for (int i = 0; i < 4; i++)
            #pragma unroll
            for (int j = 0; j < 4; j++)
                acc[i][j] = __builtin_amdgcn_mfma_f32_16x16x32_bf16(
                    af[i], bfr[j], acc[i][j], 0, 0, 0);
        __syncthreads();
    }

    // epilogue: C/D layout col = lane&15, row = quad*4 + reg
    #pragma unroll
    for (int i = 0; i < 4; i++) {
        #pragma unroll
        for (int j = 0; j < 4; j++) {
            #pragma unroll
            for (int r = 0; r < 4; r++) {
                int row = m0 + wr * 64 + i * 16 + quad * 4 + r;
                int col = n0 + wc * 64 + j * 16 + lane16;
                C[(size_t)row * N_TOT + col] = __float2bfloat16(acc[i][j][r]);
            }
        }
    }
}

// ---------------------------------------------------------------------------
// K4: per-edge dot. One wave handles 4 edges; block = 4 waves = 16 edges of
// one batch. Lane l reads elements {c*512 + l*8 .. +7} for c in 0..3 (whole
// Q=2048 row per wave, coalesced 1KB/instr). Linearity: one shuffle-reduce
// per wave covers all 4 weighted edge dots. One atomic per block.
#define EPB 16   // edges per block
__global__ __launch_bounds__(256) void edge_dot(const __hip_bfloat16* __restrict__ PAb,
                                                const __hip_bfloat16* __restrict__ Pb,
                                                const int* __restrict__ esrc,
                                                const int* __restrict__ edst,
                                                const float* __restrict__ ew,
                                                float* __restrict__ adj_acc) {
    const int b = blockIdx.y;
    const int t = threadIdx.x;
    const int w = t >> 6;
    const int l = t & 63;
    const int e_base = blockIdx.x * EPB + w * 4;

    const unsigned short* PAbase = (const unsigned short*)PAb + (size_t)b * NLOG * Q;
    const unsigned short* Pbase  = (const unsigned short*)Pb  + (size_t)b * NLOG * Q;

    float accw = 0.f;
    #pragma unroll
    for (int k = 0; k < 4; k++) {
        int e = e_base + k;
        int src = esrc[b * NEDGE + e];
        int dst = edst[b * NEDGE + e];
        float wgt = ew[b * NEDGE + e];
        const unsigned short* gi = PAbase + (size_t)src * Q + l * 8;
        const unsigned short* gj = Pbase  + (size_t)dst * Q + l * 8;
        float s = 0.f;
        #pragma unroll
        for (int c = 0; c < 4; c++) {
            us8 a = *(const us8*)(gi + c * 512);
            us8 bb = *(const us8*)(gj + c * 512);
            #pragma unroll
            for (int u = 0; u < 8; u++) {
                float fa = __uint_as_float((unsigned)a[u] << 16);
                float fb = __uint_as_float((unsigned)bb[u] << 16);
                s += fa * fb;
            }
        }
        accw += wgt * s;
    }
    // wave reduce (width 64)
    #pragma unroll
    for (int off = 32; off > 0; off >>= 1) accw += __shfl_xor(accw, off);
    __shared__ float wred[4];
    if (l == 0) wred[w] = accw;
    __syncthreads();
    if (t == 0)
        atomicAdd(&adj_acc[b], wred[0] + wred[1] + wred[2] + wred[3]);
}

// ---------------------------------------------------------------------------
// K5: loss = -mean_b( adj_acc[b] / max(sum_e w, eps) )
__global__ __launch_bounds__(256) void finalize(const float* __restrict__ ew,
                                                const float* __restrict__ adj_acc,
                                                float* __restrict__ out) {
    __shared__ float red[256];
    __shared__ float loss_s;
    int t = threadIdx.x;
    if (t == 0) loss_s = 0.f;
    for (int b = 0; b < BATCH; b++) {
        float s = 0.f;
        for (int e = t; e < NEDGE; e += 256) s += ew[b * NEDGE + e];
        red[t] = s;
        __syncthreads();
        for (int st = 128; st > 0; st >>= 1) {
            if (t < st) red[t] += red[t + st];
            __syncthreads();
        }
        if (t == 0) loss_s += adj_acc[b] / fmaxf(red[0], 1e-8f);
        __syncthreads();
    }
    if (t == 0) out[0] = -loss_s / (float)BATCH;
}

// ---------------------------------------------------------------------------
extern "C" void kernel_launch(void* const* d_in, const int* in_sizes, int n_in,
                              void* d_out, int out_size, void* d_ws, size_t ws_size,
                              hipStream_t stream) {
    const float* P    = (const float*)d_in[0];
    const int* d_hw   = (const int*)d_in[1];
    const int* esrc   = (const int*)d_in[2];
    const int* edst   = (const int*)d_in[3];
    const float* ew   = (const float*)d_in[4];
    float* out        = (float*)d_out;

    char* ws = (char*)d_ws;
    __hip_bfloat16* Pb  = (__hip_bfloat16*)ws;
    __hip_bfloat16* Abt = (__hip_bfloat16*)(ws + 33554432);
    __hip_bfloat16* PAb = (__hip_bfloat16*)(ws + 41943040);
    float* adj          = (float*)(ws + 75497472);

    hipMemsetAsync(adj, 0, BATCH * sizeof(float), stream);

    cvt_p<<<M_TOT * Q / (256 * 4), 256, 0, stream>>>(P, Pb);
    build_abt<<<dim3(Q / 32, Q / 32), 256, 0, stream>>>(d_hw, Abt);
    gemm_bt<<<dim3(M_TOT / 128, N_TOT / 128), 256, 0, stream>>>(
        (const short*)Pb, (const short*)Abt, PAb);
    edge_dot<<<dim3(NEDGE / EPB, BATCH), 256, 0, stream>>>(PAb, Pb, esrc, edst, ew, adj);
    finalize<<<1, 256, 0, stream>>>(ew, adj, out);
}